// Round 8
// baseline (281.796 us; speedup 1.0000x reference)
//
#include <hip/hip_runtime.h>

#define B 256
#define T 2048
#define L 48
#define G 16           // segments per batch chain
#define SEG 128        // steps per segment (last: 127)
#define KNORM 4.371f   // per-step constant renorm: ln(48*e^0.5)
#define TOTALF (B * T * L)

typedef short v4s __attribute__((ext_vector_type(4)));
typedef short v8s __attribute__((ext_vector_type(8)));
typedef float v4f __attribute__((ext_vector_type(4)));
typedef int   v2i __attribute__((ext_vector_type(2)));

// Wave-local ordering fence: drain LDS/SMEM counter, no s_barrier.
#define WAVE_SYNC() asm volatile("s_waitcnt lgkmcnt(0)" ::: "memory")

#if __has_builtin(__builtin_amdgcn_mfma_f32_16x16x16bf16_1k)
#define MFMA16(a, b, c) __builtin_amdgcn_mfma_f32_16x16x16bf16_1k((a), (b), (c), 0, 0, 0)
#else
__device__ __forceinline__ v4f mfma16_asm(v4s a, v4s b, v4f c) {
    asm volatile("v_mfma_f32_16x16x16_bf16 %0, %1, %2, %0\n\ts_nop 7\n\ts_nop 7"
                 : "+v"(c) : "v"(a), "v"(b));
    return c;
}
#define MFMA16(a, b, c) mfma16_asm((a), (b), (c))
#endif

// gfx950 doubled-K bf16 MFMA with self-consistent sigma slot labeling
// (slot (q,e) == state row 4q+e for e<4, 16+4q+(e-4) for e>=4) shared by A
// and B, so the reduction is layout-invariant.  B-frag = concat of the two
// K=16-style state tiles: zero data movement.  (Verified correct in R3.)
// R5 lesson: keep the C-in chained MFMA pair (pipelined forwarding); do NOT
// split into separate accumulators + VALU merge (+22 us).
#if __has_builtin(__builtin_amdgcn_mfma_f32_16x16x32_bf16)
typedef __bf16 v8y __attribute__((ext_vector_type(8)));
__device__ __forceinline__ v4f mfma32(v8s a, v8s b, v4f c) {
    return __builtin_amdgcn_mfma_f32_16x16x32_bf16(
        __builtin_bit_cast(v8y, a), __builtin_bit_cast(v8y, b), c, 0, 0, 0);
}
#else
__device__ __forceinline__ v4f mfma32(v8s a, v8s b, v4f c) {
    asm volatile("v_mfma_f32_16x16x32_bf16 %0, %1, %2, %0\n\ts_nop 7\n\ts_nop 7"
                 : "+v"(c) : "v"(a), "v"(b));
    return c;
}
#endif

// HW RNE pack: bf16(lo) -> bits 15:0, bf16(hi) -> bits 31:16 (T12 recipe).
__device__ __forceinline__ unsigned cvt_pk(float lo, float hi) {
    unsigned r;
    asm("v_cvt_pk_bf16_f32 %0, %1, %2" : "=v"(r) : "v"(lo), "v"(hi));
    return r;
}

// (C .* g) rounded to bf16 fragment: 4 mul + 2 cvt_pk
__device__ __forceinline__ v4s scale_pack(v4f cf, v4f g) {
    v4f a = cf * g;
    v2i d;
    d.x = (int)cvt_pk(a.x, a.y);
    d.y = (int)cvt_pk(a.z, a.w);
    return __builtin_bit_cast(v4s, d);
}

__device__ __forceinline__ v8s fuse01(v4s n0, v4s n1) {
    v2i a_ = __builtin_bit_cast(v2i, n0);
    v2i b_ = __builtin_bit_cast(v2i, n1);
    int4 fw; fw.x = a_.x; fw.y = a_.y; fw.z = b_.x; fw.w = b_.y;
    return __builtin_bit_cast(v8s, fw);
}

// ---------------------------------------------------------------------------
// Segment scan, column-split, BARRIER-FREE: one wave per workgroup; wg
// (b,s,ct) owns 16-column slice ct of Q_s = prod_t [D(g_t) E^T / e^K].
// Per step (identical math to the verified R3 kernel): 3x mfma_16x16x32
// chained into 3x mfma_16x16x16 + g-scale + cvt_pk pack.
// R7 lesson: occupancy was never the limit; per-SIMD issue is ~80% saturated
// (MFMA+VALU additive within a SIMD) and the residual stall is the 2x/8-step
// full-drain s_barrier convoy that phase-locks the wg's 3 waves.  Fix: each
// wave stages its own g copy into its own LDS (3 KB), ordered only by
// wave-local lgkmcnt -- zero s_barrier in the kernel.  Staging bytes issue
// 3x (L2/L3 absorb; HBM was at 6% of peak).
// ---------------------------------------------------------------------------
__global__ __launch_bounds__(64) void crf_scan(
    const float* __restrict__ em, const int* __restrict__ tags,
    const float* __restrict__ trans, float* __restrict__ out,
    float* __restrict__ ws)
{
    const int idx = blockIdx.x;          // ((b*G + s)*3 + ct)
    const int ct  = idx % 3;
    const int bs  = idx / 3;
    const int s   = bs & 15;
    const int b   = bs >> 4;
    const int ln  = threadIdx.x;         // 0..63
    const int q   = ln >> 4;             // 0..3
    const int c   = ln & 15;             // 0..15

    __shared__ __align__(16) float smem[2 * 384];   // 8 g-rows x 2 buffers (per-wave)

    const size_t bem = (size_t)b * T * L;
    const int t0 = 1 + SEG * s;
    const int t1 = (t0 + SEG < T) ? (t0 + SEG) : T;   // s=15 -> 127 steps

    // A fragments of E^T = exp(trans)^T.
    // x32 part, sigma labeling: elem e<4 -> j = 4q+e; e>=4 -> j = 16+4q+(e-4).
    v8s A32[3];
    #pragma unroll
    for (int rt = 0; rt < 3; ++rt) {
        const int m = 16 * rt + c;
        uint4 aw;
        aw.x = cvt_pk(__expf(trans[(4 * q + 0) * L + m]),
                      __expf(trans[(4 * q + 1) * L + m]));
        aw.y = cvt_pk(__expf(trans[(4 * q + 2) * L + m]),
                      __expf(trans[(4 * q + 3) * L + m]));
        aw.z = cvt_pk(__expf(trans[(16 + 4 * q + 0) * L + m]),
                      __expf(trans[(16 + 4 * q + 1) * L + m]));
        aw.w = cvt_pk(__expf(trans[(16 + 4 * q + 2) * L + m]),
                      __expf(trans[(16 + 4 * q + 3) * L + m]));
        A32[rt] = __builtin_bit_cast(v8s, aw);
    }
    // x16 part (state rows 32..47): elem e: j = 32+4q+e, row m = 16rt+c.
    v4s A16[3];
    #pragma unroll
    for (int rt = 0; rt < 3; ++rt) {
        const int m = 16 * rt + c;
        v2i d;
        d.x = (int)cvt_pk(__expf(trans[(32 + 4 * q + 0) * L + m]),
                          __expf(trans[(32 + 4 * q + 1) * L + m]));
        d.y = (int)cvt_pk(__expf(trans[(32 + 4 * q + 2) * L + m]),
                          __expf(trans[(32 + 4 * q + 3) * L + m]));
        A16[rt] = __builtin_bit_cast(v4s, d);
    }

    // State slice, col = 16ct+c.  Bq01 words: [rows 4q,4q+1][4q+2,4q+3]
    // [16+4q,16+4q+1][16+4q+2,16+4q+3]; Bq2 words: [32+4q,+1][+2,+3].
    // Init identity.
    const int col = 16 * ct + c;
    v8s Bq01;
    v4s Bq2;
    {
        int4 w;
        w.x = (4 * q + 0 == col ? 0x3F80 : 0) | (4 * q + 1 == col ? 0x3F800000 : 0);
        w.y = (4 * q + 2 == col ? 0x3F80 : 0) | (4 * q + 3 == col ? 0x3F800000 : 0);
        w.z = (16 + 4 * q + 0 == col ? 0x3F80 : 0) | (16 + 4 * q + 1 == col ? 0x3F800000 : 0);
        w.w = (16 + 4 * q + 2 == col ? 0x3F80 : 0) | (16 + 4 * q + 3 == col ? 0x3F800000 : 0);
        Bq01 = __builtin_bit_cast(v8s, w);
        v2i d2;
        d2.x = (32 + 4 * q + 0 == col ? 0x3F80 : 0) | (32 + 4 * q + 1 == col ? 0x3F800000 : 0);
        d2.y = (32 + 4 * q + 2 == col ? 0x3F80 : 0) | (32 + 4 * q + 3 == col ? 0x3F800000 : 0);
        Bq2 = __builtin_bit_cast(v4s, d2);
    }

    const v4f zero4 = {0.f, 0.f, 0.f, 0.f};   // persistent C-in

    auto do_step = [&](const float* rowp) {
        v4f gv0 = *(const v4f*)(rowp + 4 * q);
        v4f gv1 = *(const v4f*)(rowp + 16 + 4 * q);
        v4f gv2 = *(const v4f*)(rowp + 32 + 4 * q);
        v4f Cf0, Cf1, Cf2;
        {
            v4f acc = mfma32(A32[0], Bq01, zero4);
            Cf0 = MFMA16(A16[0], Bq2, acc);
        }
        {
            v4f acc = mfma32(A32[1], Bq01, zero4);
            Cf1 = MFMA16(A16[1], Bq2, acc);
        }
        {
            v4f acc = mfma32(A32[2], Bq01, zero4);
            Cf2 = MFMA16(A16[2], Bq2, acc);
        }
        v4s n0 = scale_pack(Cf0, gv0);
        v4s n1 = scale_pack(Cf1, gv1);
        Bq01 = fuse01(n0, n1);
        Bq2  = scale_pack(Cf2, gv2);
    };

    // stage g-rows t0..t0+7 into buffer 0 (wave-local: 6 floats/lane)
    {
        size_t gf = bem + (size_t)t0 * L;
        #pragma unroll
        for (int j = 0; j < 6; ++j)
            smem[ln + 64 * j] = __expf(em[gf + ln + 64 * j] - KNORM);
        WAVE_SYNC();
    }

    for (int bk = 0; bk < 16; ++bk) {
        const float* cur = smem + (bk & 1) * 384;
        float* nxt = smem + ((bk & 1) ^ 1) * 384;

        size_t gf = bem + (size_t)(t0 + 8 * (bk + 1)) * L;
        if (gf > (size_t)TOTALF - 384) gf = (size_t)TOTALF - 384;
        float stg[6];
        #pragma unroll
        for (int j = 0; j < 6; ++j) stg[j] = em[gf + ln + 64 * j];

        #pragma unroll
        for (int k = 0; k < 8; ++k)
            if (t0 + 8 * bk + k < t1)            // wave-uniform guard
                do_step(cur + 48 * k);

        #pragma unroll
        for (int j = 0; j < 6; ++j)
            nxt[ln + 64 * j] = __expf(stg[j] - KNORM);
        WAVE_SYNC();                              // writes drained before next reads
    }

    // store this wave's 16-col slice of Q, bf16 row-major [row*48+col]
    unsigned short* qs = (unsigned short*)ws + (size_t)(b * G + s) * 2304;
    v2i dt[3];
    {
        int4 w01 = __builtin_bit_cast(int4, Bq01);
        dt[0].x = w01.x; dt[0].y = w01.y;
        dt[1].x = w01.z; dt[1].y = w01.w;
        dt[2] = __builtin_bit_cast(v2i, Bq2);
    }
    #pragma unroll
    for (int kt = 0; kt < 3; ++kt) {
        v2i d = dt[kt];
        int r0 = 16 * kt + 4 * q;
        qs[(r0 + 0) * 48 + col] = (unsigned short)((unsigned)d.x & 0xffffu);
        qs[(r0 + 1) * 48 + col] = (unsigned short)((unsigned)d.x >> 16);
        qs[(r0 + 2) * 48 + col] = (unsigned short)((unsigned)d.y & 0xffffu);
        qs[(r0 + 3) * 48 + col] = (unsigned short)((unsigned)d.y >> 16);
    }

    // fused gold score for t in [128 s, 128 s + 128): ct==0 wg only,
    // two passes of 64 lanes; wave-reduce; one atomic.
    if (ct == 0) {
        const int* tg = tags + (size_t)b * T;
        float gp = 0.f;
        #pragma unroll
        for (int j = 0; j < 2; ++j) {
            int t = SEG * s + 64 * j + ln;
            int tag = tg[t];
            gp += em[bem + (size_t)t * L + tag];
            if (t < T - 1)  gp += trans[tag * L + tg[t + 1]];
            if (t == 0)     gp += trans[tag];
            if (t == T - 1) gp += trans[tag * L + (L - 1)];
        }
        #pragma unroll
        for (int off = 32; off; off >>= 1) gp += __shfl_xor(gp, off);
        if (ln == 0) atomicAdd(out, -gp);
    }
}

// ---------------------------------------------------------------------------
// Combine: per batch, u = alpha_0; for s: u = Q_s u (renormed, bf16 rows,
// next-segment register prefetch); Z_b = log(sum u_i E[i][end]) + 2047*K +
// accumulated renorm logs.  Lane l owns row l => no cross-lane reduce.
// ---------------------------------------------------------------------------
__global__ __launch_bounds__(64) void crf_combine(
    const float* __restrict__ em, const float* __restrict__ trans,
    const float* __restrict__ ws, float* __restrict__ out)
{
    const int b = blockIdx.x, l = threadIdx.x;
    const int lc = (l < L) ? l : (L - 1);

    __shared__ float us[64];

    const unsigned short* qb = (const unsigned short*)ws + (size_t)b * G * 2304;

    float u = (l < L) ? __expf(trans[l] + em[(size_t)b * T * L + l]) : 0.f;
    float logtot = 2047.0f * KNORM;

    uint4 pre[6];
    {
        const uint4* p = (const uint4*)(qb + lc * 48);
        #pragma unroll
        for (int ii = 0; ii < 6; ++ii) pre[ii] = p[ii];
    }

    for (int s = 0; s < G; ++s) {
        us[l] = u;
        uint4 cur[6];
        #pragma unroll
        for (int ii = 0; ii < 6; ++ii) cur[ii] = pre[ii];
        if (s + 1 < G) {
            const uint4* p = (const uint4*)(qb + (size_t)(s + 1) * 2304 + lc * 48);
            #pragma unroll
            for (int ii = 0; ii < 6; ++ii) pre[ii] = p[ii];
        }
        WAVE_SYNC();

        float acc = 0.f;
        #pragma unroll
        for (int ii = 0; ii < 6; ++ii) {
            unsigned w0 = cur[ii].x, w1 = cur[ii].y, w2 = cur[ii].z, w3 = cur[ii].w;
            int jj = ii * 8;
            acc = fmaf(__uint_as_float(w0 << 16),          us[jj + 0], acc);
            acc = fmaf(__uint_as_float(w0 & 0xffff0000u),  us[jj + 1], acc);
            acc = fmaf(__uint_as_float(w1 << 16),          us[jj + 2], acc);
            acc = fmaf(__uint_as_float(w1 & 0xffff0000u),  us[jj + 3], acc);
            acc = fmaf(__uint_as_float(w2 << 16),          us[jj + 4], acc);
            acc = fmaf(__uint_as_float(w2 & 0xffff0000u),  us[jj + 5], acc);
            acc = fmaf(__uint_as_float(w3 << 16),          us[jj + 6], acc);
            acc = fmaf(__uint_as_float(w3 & 0xffff0000u),  us[jj + 7], acc);
        }
        WAVE_SYNC();   // us reads done before next overwrite

        float r = __int_as_float(
            __builtin_amdgcn_readlane(__float_as_int(acc), 0));
        logtot += __logf(r);
        u = (l < L) ? acc * __builtin_amdgcn_rcpf(r) : 0.f;
    }

    float v = (l < L) ? u * __expf(trans[lc * L + (L - 1)]) : 0.f;
    #pragma unroll
    for (int off = 32; off; off >>= 1) v += __shfl_xor(v, off);
    if (l == 0) atomicAdd(out, logtot + __logf(v));
}

extern "C" void kernel_launch(void* const* d_in, const int* in_sizes, int n_in,
                              void* d_out, int out_size, void* d_ws, size_t ws_size,
                              hipStream_t stream) {
    const float* em    = (const float*)d_in[0];   // (B, T, L) f32
    const int*   tags  = (const int*)  d_in[1];   // (B, T) i32
    const float* trans = (const float*)d_in[2];   // (L, L) f32
    float* out = (float*)d_out;
    float* ws  = (float*)d_ws;                    // 4096 * 2304 bf16 = 18.9 MB

    (void)hipMemsetAsync(out, 0, sizeof(float), stream);
    crf_scan   <<<B * G * 3, 64, 0, stream>>>(em, tags, trans, out, ws);
    crf_combine<<<B,         64, 0, stream>>>(em, trans, ws, out);
}

// Round 11
// 257.789 us; speedup vs baseline: 1.0931x; 1.0931x over previous
//
#include <hip/hip_runtime.h>

#define B 256
#define T 2048
#define L 48
#define G 16           // segments per batch chain
#define SEG 128        // steps per segment (last: 127)
#define KNORM 4.371f   // per-step constant renorm: ln(48*e^0.5)
#define TOTALF (B * T * L)

typedef short v4s __attribute__((ext_vector_type(4)));
typedef short v8s __attribute__((ext_vector_type(8)));
typedef float v4f __attribute__((ext_vector_type(4)));
typedef int   v2i __attribute__((ext_vector_type(2)));

// Single-wave "barrier" (combine kernel only): drain LDS counters, not vmcnt.
#define WAVE_SYNC() asm volatile("s_waitcnt lgkmcnt(0)" ::: "memory")

#if __has_builtin(__builtin_amdgcn_mfma_f32_16x16x16bf16_1k)
#define MFMA16(a, b, c) __builtin_amdgcn_mfma_f32_16x16x16bf16_1k((a), (b), (c), 0, 0, 0)
#else
__device__ __forceinline__ v4f mfma16_asm(v4s a, v4s b, v4f c) {
    asm volatile("v_mfma_f32_16x16x16_bf16 %0, %1, %2, %0\n\ts_nop 7\n\ts_nop 7"
                 : "+v"(c) : "v"(a), "v"(b));
    return c;
}
#define MFMA16(a, b, c) mfma16_asm((a), (b), (c))
#endif

// gfx950 doubled-K bf16 MFMA with self-consistent sigma slot labeling
// (slot (q,e) == state row 4q+e for e<4, 16+4q+(e-4) for e>=4) shared by A
// and B, so the reduction is layout-invariant.  B-frag = concat of the two
// K=16-style state tiles: zero data movement.  (Verified correct in R3.)
// R5 lesson: keep the C-in chained MFMA pair (pipelined forwarding); do NOT
// split into separate accumulators + VALU merge (+22 us).
// R8 lesson: the barrier convoy was NOT the stall (barrier-free was worse).
// R9/R10 lesson: control-flow restructures of this loop (guard peel,
// sequential-2) NaN for unidentified reasons while this guarded shape
// always passes -- keep the guarded structure.
#if __has_builtin(__builtin_amdgcn_mfma_f32_16x16x32_bf16)
typedef __bf16 v8y __attribute__((ext_vector_type(8)));
__device__ __forceinline__ v4f mfma32(v8s a, v8s b, v4f c) {
    return __builtin_amdgcn_mfma_f32_16x16x32_bf16(
        __builtin_bit_cast(v8y, a), __builtin_bit_cast(v8y, b), c, 0, 0, 0);
}
#else
__device__ __forceinline__ v4f mfma32(v8s a, v8s b, v4f c) {
    asm volatile("v_mfma_f32_16x16x32_bf16 %0, %1, %2, %0\n\ts_nop 7\n\ts_nop 7"
                 : "+v"(c) : "v"(a), "v"(b));
    return c;
}
#endif

// HW RNE pack: bf16(lo) -> bits 15:0, bf16(hi) -> bits 31:16 (T12 recipe).
__device__ __forceinline__ unsigned cvt_pk(float lo, float hi) {
    unsigned r;
    asm("v_cvt_pk_bf16_f32 %0, %1, %2" : "=v"(r) : "v"(lo), "v"(hi));
    return r;
}

// (C .* g) rounded to bf16 fragment: 4 mul + 2 cvt_pk
__device__ __forceinline__ v4s scale_pack(v4f cf, v4f g) {
    v4f a = cf * g;
    v2i d;
    d.x = (int)cvt_pk(a.x, a.y);
    d.y = (int)cvt_pk(a.z, a.w);
    return __builtin_bit_cast(v4s, d);
}

__device__ __forceinline__ v8s fuse01(v4s n0, v4s n1) {
    v2i a_ = __builtin_bit_cast(v2i, n0);
    v2i b_ = __builtin_bit_cast(v2i, n1);
    int4 fw; fw.x = a_.x; fw.y = a_.y; fw.z = b_.x; fw.w = b_.y;
    return __builtin_bit_cast(v8s, fw);
}

// ---------------------------------------------------------------------------
// Segment scan, column-split: workgroup (b,s) = 192 threads = 3 waves; wave w
// owns 16-column slice ct=w of Q_s = prod_t [D(g_t) E^T / e^K].  Per wave per
// step: 3x mfma_16x16x32 (state rows 0..31) chained into 3x mfma_16x16x16
// (rows 32..47) + g-scale + cvt_pk bf16 pack.  This is the R3 kernel,
// measured 262.0 us total / 158 us scan (MfmaUtil 42%, VALUBusy 37%),
// resubmitted verbatim after two failed restructure attempts (R9/R10 NaN).
// Ceiling model: 247 cyc/wave-step wall vs ~190 cyc/step summed MFMA+VALU
// pipe demand (additive within a SIMD); the constant ~100-105 us non-scan
// gap across all measured rounds is harness-fixed overhead.
// ---------------------------------------------------------------------------
__global__ __launch_bounds__(192, 6) void crf_scan(
    const float* __restrict__ em, const int* __restrict__ tags,
    const float* __restrict__ trans, float* __restrict__ out,
    float* __restrict__ ws)
{
    const int b   = blockIdx.x >> 4;
    const int s   = blockIdx.x & 15;
    const int tid = threadIdx.x;
    const int ct  = tid >> 6;          // wave = column tile 0..2
    const int ln  = tid & 63;
    const int q   = ln >> 4;           // 0..3
    const int c   = ln & 15;           // 0..15

    __shared__ __align__(16) float smem[2 * 384];   // 8 g-rows x 2 buffers

    const size_t bem = (size_t)b * T * L;
    const int t0 = 1 + SEG * s;
    const int t1 = (t0 + SEG < T) ? (t0 + SEG) : T;   // s=15 -> 127 steps

    // A fragments of E^T = exp(trans)^T.
    // x32 part, sigma labeling: elem e<4 -> j = 4q+e; e>=4 -> j = 16+4q+(e-4).
    v8s A32[3];
    #pragma unroll
    for (int rt = 0; rt < 3; ++rt) {
        const int m = 16 * rt + c;
        uint4 aw;
        aw.x = cvt_pk(__expf(trans[(4 * q + 0) * L + m]),
                      __expf(trans[(4 * q + 1) * L + m]));
        aw.y = cvt_pk(__expf(trans[(4 * q + 2) * L + m]),
                      __expf(trans[(4 * q + 3) * L + m]));
        aw.z = cvt_pk(__expf(trans[(16 + 4 * q + 0) * L + m]),
                      __expf(trans[(16 + 4 * q + 1) * L + m]));
        aw.w = cvt_pk(__expf(trans[(16 + 4 * q + 2) * L + m]),
                      __expf(trans[(16 + 4 * q + 3) * L + m]));
        A32[rt] = __builtin_bit_cast(v8s, aw);
    }
    // x16 part (state rows 32..47): elem e: j = 32+4q+e, row m = 16rt+c.
    v4s A16[3];
    #pragma unroll
    for (int rt = 0; rt < 3; ++rt) {
        const int m = 16 * rt + c;
        v2i d;
        d.x = (int)cvt_pk(__expf(trans[(32 + 4 * q + 0) * L + m]),
                          __expf(trans[(32 + 4 * q + 1) * L + m]));
        d.y = (int)cvt_pk(__expf(trans[(32 + 4 * q + 2) * L + m]),
                          __expf(trans[(32 + 4 * q + 3) * L + m]));
        A16[rt] = __builtin_bit_cast(v4s, d);
    }

    // State slice, col = 16ct+c.  Bq01 words: [rows 4q,4q+1][4q+2,4q+3]
    // [16+4q,16+4q+1][16+4q+2,16+4q+3]; Bq2 words: [32+4q,+1][+2,+3].
    // Init identity.
    const int col = 16 * ct + c;
    v8s Bq01;
    v4s Bq2;
    {
        int4 w;
        w.x = (4 * q + 0 == col ? 0x3F80 : 0) | (4 * q + 1 == col ? 0x3F800000 : 0);
        w.y = (4 * q + 2 == col ? 0x3F80 : 0) | (4 * q + 3 == col ? 0x3F800000 : 0);
        w.z = (16 + 4 * q + 0 == col ? 0x3F80 : 0) | (16 + 4 * q + 1 == col ? 0x3F800000 : 0);
        w.w = (16 + 4 * q + 2 == col ? 0x3F80 : 0) | (16 + 4 * q + 3 == col ? 0x3F800000 : 0);
        Bq01 = __builtin_bit_cast(v8s, w);
        v2i d2;
        d2.x = (32 + 4 * q + 0 == col ? 0x3F80 : 0) | (32 + 4 * q + 1 == col ? 0x3F800000 : 0);
        d2.y = (32 + 4 * q + 2 == col ? 0x3F80 : 0) | (32 + 4 * q + 3 == col ? 0x3F800000 : 0);
        Bq2 = __builtin_bit_cast(v4s, d2);
    }

    const v4f zero4 = {0.f, 0.f, 0.f, 0.f};   // persistent C-in

    auto do_step = [&](const float* rowp) {
        v4f gv0 = *(const v4f*)(rowp + 4 * q);
        v4f gv1 = *(const v4f*)(rowp + 16 + 4 * q);
        v4f gv2 = *(const v4f*)(rowp + 32 + 4 * q);
        v4f Cf0, Cf1, Cf2;
        {
            v4f acc = mfma32(A32[0], Bq01, zero4);
            Cf0 = MFMA16(A16[0], Bq2, acc);
        }
        {
            v4f acc = mfma32(A32[1], Bq01, zero4);
            Cf1 = MFMA16(A16[1], Bq2, acc);
        }
        {
            v4f acc = mfma32(A32[2], Bq01, zero4);
            Cf2 = MFMA16(A16[2], Bq2, acc);
        }
        v4s n0 = scale_pack(Cf0, gv0);
        v4s n1 = scale_pack(Cf1, gv1);
        Bq01 = fuse01(n0, n1);
        Bq2  = scale_pack(Cf2, gv2);
    };

    // stage g-rows t0..t0+7 into buffer 0 (cooperative: 2 floats/lane)
    {
        size_t gf = bem + (size_t)t0 * L;
        smem[tid]       = __expf(em[gf + tid]       - KNORM);
        smem[tid + 192] = __expf(em[gf + tid + 192] - KNORM);
        __syncthreads();
    }

    for (int bk = 0; bk < 16; ++bk) {
        const float* cur = smem + (bk & 1) * 384;
        float* nxt = smem + ((bk & 1) ^ 1) * 384;

        size_t gf = bem + (size_t)(t0 + 8 * (bk + 1)) * L;
        if (gf > (size_t)TOTALF - 384) gf = (size_t)TOTALF - 384;
        float stg0 = em[gf + tid];
        float stg1 = em[gf + tid + 192];

        #pragma unroll
        for (int k = 0; k < 8; ++k)
            if (t0 + 8 * bk + k < t1)            // workgroup-uniform guard
                do_step(cur + 48 * k);

        nxt[tid]       = __expf(stg0 - KNORM);
        nxt[tid + 192] = __expf(stg1 - KNORM);
        __syncthreads();
    }

    // store this wave's 16-col slice of Q, bf16 row-major [row*48+col]
    unsigned short* qs = (unsigned short*)ws + (size_t)(b * G + s) * 2304;
    v2i dt[3];
    {
        int4 w01 = __builtin_bit_cast(int4, Bq01);
        dt[0].x = w01.x; dt[0].y = w01.y;
        dt[1].x = w01.z; dt[1].y = w01.w;
        dt[2] = __builtin_bit_cast(v2i, Bq2);
    }
    #pragma unroll
    for (int kt = 0; kt < 3; ++kt) {
        v2i d = dt[kt];
        int r0 = 16 * kt + 4 * q;
        qs[(r0 + 0) * 48 + col] = (unsigned short)((unsigned)d.x & 0xffffu);
        qs[(r0 + 1) * 48 + col] = (unsigned short)((unsigned)d.x >> 16);
        qs[(r0 + 2) * 48 + col] = (unsigned short)((unsigned)d.y & 0xffffu);
        qs[(r0 + 3) * 48 + col] = (unsigned short)((unsigned)d.y >> 16);
    }

    // fused gold score for t in [128 s, 128 s + 128): one t per lane, tid<128
    const int* tg = tags + (size_t)b * T;
    float gp = 0.f;
    if (tid < 128) {
        int t = SEG * s + tid;
        int tag = tg[t];
        gp += em[bem + (size_t)t * L + tag];
        if (t < T - 1)  gp += trans[tag * L + tg[t + 1]];
        if (t == 0)     gp += trans[tag];
        if (t == T - 1) gp += trans[tag * L + (L - 1)];
    }
    #pragma unroll
    for (int off = 32; off; off >>= 1) gp += __shfl_xor(gp, off);
    __shared__ float red[3];
    if (ln == 0) red[ct] = gp;
    __syncthreads();
    if (tid == 0) atomicAdd(out, -(red[0] + red[1] + red[2]));
}

// ---------------------------------------------------------------------------
// Combine: per batch, u = alpha_0; for s: u = Q_s u (renormed, bf16 rows,
// next-segment register prefetch); Z_b = log(sum u_i E[i][end]) + 2047*K +
// accumulated renorm logs.  Lane l owns row l => no cross-lane reduce.
// ---------------------------------------------------------------------------
__global__ __launch_bounds__(64) void crf_combine(
    const float* __restrict__ em, const float* __restrict__ trans,
    const float* __restrict__ ws, float* __restrict__ out)
{
    const int b = blockIdx.x, l = threadIdx.x;
    const int lc = (l < L) ? l : (L - 1);

    __shared__ float us[64];

    const unsigned short* qb = (const unsigned short*)ws + (size_t)b * G * 2304;

    float u = (l < L) ? __expf(trans[l] + em[(size_t)b * T * L + l]) : 0.f;
    float logtot = 2047.0f * KNORM;

    uint4 pre[6];
    {
        const uint4* p = (const uint4*)(qb + lc * 48);
        #pragma unroll
        for (int ii = 0; ii < 6; ++ii) pre[ii] = p[ii];
    }

    for (int s = 0; s < G; ++s) {
        us[l] = u;
        uint4 cur[6];
        #pragma unroll
        for (int ii = 0; ii < 6; ++ii) cur[ii] = pre[ii];
        if (s + 1 < G) {
            const uint4* p = (const uint4*)(qb + (size_t)(s + 1) * 2304 + lc * 48);
            #pragma unroll
            for (int ii = 0; ii < 6; ++ii) pre[ii] = p[ii];
        }
        WAVE_SYNC();

        float acc = 0.f;
        #pragma unroll
        for (int ii = 0; ii < 6; ++ii) {
            unsigned w0 = cur[ii].x, w1 = cur[ii].y, w2 = cur[ii].z, w3 = cur[ii].w;
            int jj = ii * 8;
            acc = fmaf(__uint_as_float(w0 << 16),          us[jj + 0], acc);
            acc = fmaf(__uint_as_float(w0 & 0xffff0000u),  us[jj + 1], acc);
            acc = fmaf(__uint_as_float(w1 << 16),          us[jj + 2], acc);
            acc = fmaf(__uint_as_float(w1 & 0xffff0000u),  us[jj + 3], acc);
            acc = fmaf(__uint_as_float(w2 << 16),          us[jj + 4], acc);
            acc = fmaf(__uint_as_float(w2 & 0xffff0000u),  us[jj + 5], acc);
            acc = fmaf(__uint_as_float(w3 << 16),          us[jj + 6], acc);
            acc = fmaf(__uint_as_float(w3 & 0xffff0000u),  us[jj + 7], acc);
        }
        WAVE_SYNC();   // us reads done before next overwrite

        float r = __int_as_float(
            __builtin_amdgcn_readlane(__float_as_int(acc), 0));
        logtot += __logf(r);
        u = (l < L) ? acc * __builtin_amdgcn_rcpf(r) : 0.f;
    }

    float v = (l < L) ? u * __expf(trans[lc * L + (L - 1)]) : 0.f;
    #pragma unroll
    for (int off = 32; off; off >>= 1) v += __shfl_xor(v, off);
    if (l == 0) atomicAdd(out, logtot + __logf(v));
}

extern "C" void kernel_launch(void* const* d_in, const int* in_sizes, int n_in,
                              void* d_out, int out_size, void* d_ws, size_t ws_size,
                              hipStream_t stream) {
    const float* em    = (const float*)d_in[0];   // (B, T, L) f32
    const int*   tags  = (const int*)  d_in[1];   // (B, T) i32
    const float* trans = (const float*)d_in[2];   // (L, L) f32
    float* out = (float*)d_out;
    float* ws  = (float*)d_ws;                    // 4096 * 2304 bf16 = 18.9 MB

    (void)hipMemsetAsync(out, 0, sizeof(float), stream);
    crf_scan   <<<B * G, 192, 0, stream>>>(em, tags, trans, out, ws);
    crf_combine<<<B,      64, 0, stream>>>(em, trans, ws, out);
}